// Round 1
// baseline (112.965 us; speedup 1.0000x reference)
//
#include <hip/hip_runtime.h>
#include <math.h>

#define B_ 16
#define F_ 256
#define T_ 2048
#define K_ 20
#define OUTK 21

// Transpose [F][Lsrc] (col offset co) -> [T][F] per batch, plus per-column sum of squares.
__global__ __launch_bounds__(256) void transpose_norm_kernel(
    const float* __restrict__ src, float* __restrict__ dst,
    float* __restrict__ nrm, int Lsrc, int co)
{
    __shared__ float tile[256][33];  // 256 f x 32 t, +1 pad
    int b  = blockIdx.y;
    int t0 = blockIdx.x * 32;
    const float* srcb = src + (size_t)b * F_ * Lsrc;
    int tl = threadIdx.x & 31;   // t within tile
    int fl = threadIdx.x >> 5;   // 0..7
#pragma unroll
    for (int i = 0; i < 32; ++i) {
        int f = i * 8 + fl;
        tile[f][tl] = srcb[(size_t)f * Lsrc + (t0 + tl + co)];
    }
    __syncthreads();
    float* dstb = dst + ((size_t)b * T_ + t0) * F_;
#pragma unroll
    for (int j = 0; j < 32; ++j) {
        dstb[(size_t)j * F_ + threadIdx.x] = tile[threadIdx.x][j];
    }
    if (threadIdx.x < 32) {
        float s = 0.f;
#pragma unroll 8
        for (int f = 0; f < 256; ++f) { float v = tile[f][threadIdx.x]; s += v * v; }
        nrm[b * T_ + t0 + threadIdx.x] = s;
    }
}

// One 64-lane wave per (b,t): 21 cosine sims.
__global__ __launch_bounds__(64) void sim_kernel(
    const float* __restrict__ zt, const float* __restrict__ ct,
    const float* __restrict__ nz, const float* __restrict__ nc,
    const int* __restrict__ inds, float* __restrict__ out)
{
    int bt   = blockIdx.x;           // b*T + t
    int b    = bt >> 11;             // T = 2048
    int lane = threadIdx.x;

    const float4* zrow = (const float4*)(zt + (size_t)bt * F_);
    const float4* crow = (const float4*)(ct + (size_t)bt * F_);
    float4 zv = zrow[lane];
    float4 cv = crow[lane];
    float sqnz = sqrtf(nz[bt]);

    const int* myinds = inds + (size_t)bt * K_;   // flat (b*T+t)*K + k
    float* orow = out + (size_t)bt * OUTK;

    // k = 0: positive target = c column
    {
        float d = zv.x*cv.x + zv.y*cv.y + zv.z*cv.z + zv.w*cv.w;
        for (int off = 32; off; off >>= 1) d += __shfl_xor(d, off);
        if (lane == 0) {
            float den = fmaxf(sqnz * sqrtf(nc[bt]), 1e-8f);
            orow[0] = (d / den) * 2.0f;   // /TEMP, TEMP=0.5
        }
    }
    // negatives
    for (int k = 0; k < K_; ++k) {
        int idx = myinds[k];                       // in [0, T-2]
        int row = (b << 11) + idx;                 // b*T + idx
        const float4* trow = (const float4*)(zt + (size_t)row * F_);
        float4 tv = trow[lane];
        float d = zv.x*tv.x + zv.y*tv.y + zv.z*tv.z + zv.w*tv.w;
        for (int off = 32; off; off >>= 1) d += __shfl_xor(d, off);
        bool eq = (tv.x == cv.x) & (tv.y == cv.y) & (tv.z == cv.z) & (tv.w == cv.w);
        bool allq = __all(eq);                     // exact neg_is_pos mask
        if (lane == 0) {
            float den = fmaxf(sqnz * sqrtf(nz[row]), 1e-8f);
            orow[k + 1] = allq ? -INFINITY : (d / den) * 2.0f;
        }
    }
}

extern "C" void kernel_launch(void* const* d_in, const int* in_sizes, int n_in,
                              void* d_out, int out_size, void* d_ws, size_t ws_size,
                              hipStream_t stream)
{
    const float* z    = (const float*)d_in[0];
    const float* c    = (const float*)d_in[1];
    const int*   inds = (const int*)d_in[2];
    float* out = (float*)d_out;

    char* ws = (char*)d_ws;
    size_t zt_bytes = (size_t)B_ * T_ * F_ * sizeof(float);  // 32 MB
    float* zt = (float*)ws;
    float* ct = (float*)(ws + zt_bytes);
    float* nz = (float*)(ws + 2 * zt_bytes);
    float* nc = nz + B_ * T_;

    dim3 tb(256), tg(T_ / 32, B_);
    transpose_norm_kernel<<<tg, tb, 0, stream>>>(z, zt, nz, T_, 0);
    transpose_norm_kernel<<<tg, tb, 0, stream>>>(c, ct, nc, T_ + 1, 1);
    sim_kernel<<<dim3(B_ * T_), dim3(64), 0, stream>>>(zt, ct, nz, nc, inds, out);
}